// Round 2
// baseline (575.285 us; speedup 1.0000x reference)
//
#include <hip/hip_runtime.h>
#include <cfloat>

#define BB   32
#define VV   2048
#define KNB  40
#define FIN  64
#define DD   4
#define PP   64
#define NN   (BB*VV)           // 65536

static __device__ __forceinline__ float fast_tanh(float z) {
    z = fminf(fmaxf(z, -15.f), 15.f);
    float e = __expf(2.f * z);
    return (e - 1.f) / (e + 1.f);
}

// ---------------------------------------------------------------------------
// Kernel 1: coords = x@W_s + b_s (N x 4), feats = x@W_f + b_f (N x 64)
// Tiled GEMM: block = 64 rows, Xs staged transposed [k][r] for float4 A-reads,
// 4x4 register micro-tile per thread. Coords (4 cols) via a small second loop
// (1 output/thread).
// ---------------------------------------------------------------------------
__global__ __launch_bounds__(256) void k_embed(
    const float* __restrict__ x, const float* __restrict__ Ws,
    const float* __restrict__ bs, const float* __restrict__ Wf,
    const float* __restrict__ bf, float* __restrict__ coords,
    float* __restrict__ feats)
{
    __shared__ float Xs[64][68];   // [k][r], +4 pad (float4-aligned rows)
    __shared__ float Wfs[64][64];  // [k][c]
    __shared__ float Wss[64][4];   // [k][c]
    const int tid  = threadIdx.x;
    const int row0 = blockIdx.x * 64;

    #pragma unroll
    for (int i = 0; i < 4; ++i) {
        const int idx = tid + i * 256;          // 0..1023 float4s
        const int r   = idx >> 4;
        const int k4  = (idx & 15) << 2;
        float4 v = *(const float4*)(x + (size_t)(row0 + r) * FIN + k4);
        Xs[k4+0][r] = v.x; Xs[k4+1][r] = v.y; Xs[k4+2][r] = v.z; Xs[k4+3][r] = v.w;
        ((float4*)Wfs)[idx] = ((const float4*)Wf)[idx];
    }
    if (tid < 64) *(float4*)Wss[tid] = ((const float4*)Ws)[tid];
    __syncthreads();

    const int tx = tid & 15;       // cols tx*4..+3
    const int ty = tid >> 4;       // rows ty*4..+3
    float acc[4][4] = {};
    #pragma unroll 16
    for (int k = 0; k < 64; ++k) {
        float4 a = *(const float4*)&Xs[k][ty * 4];
        float4 b = *(const float4*)&Wfs[k][tx * 4];
        acc[0][0] += a.x*b.x; acc[0][1] += a.x*b.y; acc[0][2] += a.x*b.z; acc[0][3] += a.x*b.w;
        acc[1][0] += a.y*b.x; acc[1][1] += a.y*b.y; acc[1][2] += a.y*b.z; acc[1][3] += a.y*b.w;
        acc[2][0] += a.z*b.x; acc[2][1] += a.z*b.y; acc[2][2] += a.z*b.z; acc[2][3] += a.z*b.w;
        acc[3][0] += a.w*b.x; acc[3][1] += a.w*b.y; acc[3][2] += a.w*b.z; acc[3][3] += a.w*b.w;
    }
    const float4 bfv = *(const float4*)(bf + tx * 4);
    const float ar[4] = {bfv.x, bfv.y, bfv.z, bfv.w};
    #pragma unroll
    for (int i = 0; i < 4; ++i) {
        float4 o = { acc[i][0] + ar[0], acc[i][1] + ar[1],
                     acc[i][2] + ar[2], acc[i][3] + ar[3] };
        *(float4*)(feats + (size_t)(row0 + ty * 4 + i) * PP + tx * 4) = o;
    }

    // coords: one output per thread (64 rows x 4 cols)
    const int cr = tid >> 2, cc = tid & 3;
    float ca = bs[cc];
    #pragma unroll 16
    for (int k = 0; k < 64; ++k) ca += Xs[k][cr] * Wss[k][cc];
    coords[(size_t)(row0 + cr) * DD + cc] = ca;
}

// ---------------------------------------------------------------------------
// Kernel 2: exact top-40 KNN (excluding self) + weighted max/mean pooling.
// Barrier-free per-wave pipeline: hist/cand arrays are PER-WAVE, DS ops from
// one wave complete in order, so no __syncthreads inside the row loop (the
// only one guards the read-only cpos stage).
// Selection: 256-bin hist width 1/32 over [0,8) (self & far -> sentinel bin
// 270, never scanned); if the boundary bin makes >64 candidates, a fine
// 256x-finer pass; compact -> 64-lane bitonic sort by (d2,idx) -> top-40.
// Weight exp(-10*d2) comes directly from the sorted key (same expression as
// the reference's dist).
// ---------------------------------------------------------------------------
__global__ __launch_bounds__(256) void k_knn(
    const float* __restrict__ coords, const float* __restrict__ feats,
    float* __restrict__ collected)
{
    __shared__ float4 cpos[VV];        // 32 KB
    __shared__ int    hist[4][272];    // per-wave, 272 = 256 scanned + slop
    __shared__ float  candD[4][64];
    __shared__ int    candI[4][64];

    const int tid   = threadIdx.x;
    const int lane  = tid & 63;
    const int w     = tid >> 6;
    const int batch = blockIdx.x >> 7;      // 128 chunks of 16 rows per batch
    const int chunk = blockIdx.x & 127;
    const float* cb = coords + (size_t)batch * VV * DD;
    const float* fb = feats  + (size_t)batch * VV * PP;

    for (int i = tid; i < VV; i += 256) cpos[i] = ((const float4*)cb)[i];
    __syncthreads();                        // the only barrier

    const int4 izero = {0, 0, 0, 0};

    for (int rr = 0; rr < 4; ++rr) {
        const int v = (chunk << 4) + (w << 2) + rr;
        const float4 cv = cpos[v];

        // ---- distances (direct-diff form == reference's weight expression) ----
        float d2loc[32];
        #pragma unroll
        for (int j = 0; j < 32; ++j) {
            float4 cw = cpos[lane + (j << 6)];
            float dx = cv.x - cw.x, dy = cv.y - cw.y;
            float dz = cv.z - cw.z, dw = cv.w - cw.w;
            d2loc[j] = dx*dx + dy*dy + dz*dz + dw*dw;
        }
        if (lane == (v & 63)) d2loc[v >> 6] = 1e35f;   // self -> sentinel

        // ---- histogram + scan (attempt 1: [0,8) w=1/32; attempt 2: [0,128) w=1/2) ----
        float scale = 32.f;
        int g1 = 255, nb1 = 0, cntg = 0;
        for (int attempt = 0; attempt < 2; ++attempt) {
            ((int4*)hist[w])[lane] = izero;
            if (lane < 4) ((int4*)hist[w])[64 + lane] = izero;
            #pragma unroll
            for (int j = 0; j < 32; ++j) {
                int b = (int)fminf(d2loc[j] * scale, 270.f);  // >range incl self -> 256..270
                atomicAdd(&hist[w][b], 1);
            }
            const int4 hv = ((const int4*)hist[w])[lane];
            const int local = hv.x + hv.y + hv.z + hv.w;
            int incl = local;
            #pragma unroll
            for (int off = 1; off < 64; off <<= 1) {
                int t = __shfl_up(incl, off);
                if (lane >= off) incl += t;
            }
            const int total = __shfl(incl, 63);
            const int excl  = incl - local;
            const bool pred = (excl < KNB) && (excl + local >= KNB);
            unsigned long long m = __ballot(pred);
            const int src = (m == 0ull) ? 0 : (__ffsll((unsigned long long)m) - 1);
            int gg = 255, nnb = 0, cc = 0;
            if (pred) {
                const int hh[4] = {hv.x, hv.y, hv.z, hv.w};
                int cacc = excl, found = -1;
                #pragma unroll
                for (int q = 0; q < 4; ++q) {
                    if (found < 0 && cacc + hh[q] >= KNB) { found = q; nnb = cacc; cc = hh[q]; }
                    cacc += hh[q];
                }
                gg = (lane << 2) + found;
            }
            g1   = __shfl(gg, src);
            nb1  = __shfl(nnb, src);
            cntg = __shfl(cc, src);
            if (total >= KNB) break;
            scale = 2.f;
        }
        const float flo = (float)g1 / scale;            // exact: scale is 2^k
        const float fhi = (float)(g1 + 1) / scale;
        const float fscale = scale * 256.f;

        // ---- fine pass only if boundary bin overflows the 64-slot sorter ----
        int g2 = 255;                                    // common path: all of bin g1
        if (nb1 + cntg > 64) {
            ((int4*)hist[w])[lane] = izero;
            if (lane < 4) ((int4*)hist[w])[64 + lane] = izero;
            #pragma unroll
            for (int j = 0; j < 32; ++j) {
                const float d2 = d2loc[j];
                if (d2 >= flo && d2 < fhi) {
                    int b2 = (int)fminf((d2 - flo) * fscale, 255.f);
                    atomicAdd(&hist[w][b2], 1);
                }
            }
            const int need2 = KNB - nb1;
            const int4 hv = ((const int4*)hist[w])[lane];
            const int local = hv.x + hv.y + hv.z + hv.w;
            int incl = local;
            #pragma unroll
            for (int off = 1; off < 64; off <<= 1) {
                int t = __shfl_up(incl, off);
                if (lane >= off) incl += t;
            }
            const int excl = incl - local;
            const bool pred = (excl < need2) && (excl + local >= need2);
            unsigned long long m = __ballot(pred);
            const int src = (m == 0ull) ? 0 : (__ffsll((unsigned long long)m) - 1);
            int gg = 255;
            if (pred) {
                const int hh[4] = {hv.x, hv.y, hv.z, hv.w};
                int cacc = excl, found = -1;
                #pragma unroll
                for (int q = 0; q < 4; ++q) {
                    if (found < 0 && cacc + hh[q] >= need2) found = q;
                    cacc += hh[q];
                }
                gg = (lane << 2) + found;
            }
            g2 = __shfl(gg, src);
        }

        // ---- compact candidates (bin-identical expressions -> exact match) ----
        int total = 0;
        #pragma unroll
        for (int j = 0; j < 32; ++j) {
            const float d2 = d2loc[j];
            const int  b2  = (int)fminf((d2 - flo) * fscale, 255.f);
            const bool flag = (d2 < flo) || (d2 >= flo && d2 < fhi && b2 <= g2);
            unsigned long long m = __ballot(flag);
            if (flag) {
                int pos = total + (int)__popcll(m & ((1ull << lane) - 1ull));
                if (pos < 64) { candD[w][pos] = d2; candI[w][pos] = lane + (j << 6); }
            }
            total += (int)__popcll(m);
        }
        const int cnt = total < 64 ? total : 64;

        // ---- 64-lane bitonic sort ascending by (d2, idx) ----
        float sd; int si;
        if (lane < cnt) { sd = candD[w][lane]; si = candI[w][lane]; }
        else            { sd = FLT_MAX;        si = 0x7fffffff;     }
        #pragma unroll
        for (int kk = 2; kk <= 64; kk <<= 1) {
            #pragma unroll
            for (int jj = kk >> 1; jj > 0; jj >>= 1) {
                float od = __shfl_xor(sd, jj);
                int   oi = __shfl_xor(si, jj);
                const bool keepMin = (((lane & kk) == 0) == ((lane & jj) == 0));
                const bool less    = (od < sd) || (od == sd && oi < si);
                if (less == keepMin) { sd = od; si = oi; }
            }
        }

        // ---- stash (weight, idx) per-wave; pool 64 feats via LDS broadcast ----
        if (lane < KNB) {
            candD[w][lane] = __expf(-10.f * sd);
            candI[w][lane] = si < (VV - 1) ? si : (VV - 1);  // paranoia clamp
        }
        float mx = -FLT_MAX, sm = 0.f;
        #pragma unroll 8
        for (int j = 0; j < KNB; ++j) {
            const float wj = candD[w][j];
            const int   ij = candI[w][j];
            const float nv = fb[(size_t)ij * PP + lane] * wj;
            mx = fmaxf(mx, nv);
            sm += nv;
        }
        float* outp = collected + ((size_t)(batch * VV + v) << 7);
        outp[lane]      = mx;
        outp[PP + lane] = sm * (1.f / KNB);
    }
}

// ---------------------------------------------------------------------------
// Kernel 3: out = tanh(concat(x, collected) @ W_out + b_out), (N x 192)@(192 x 128)
// 64 rows x 128 cols per block, 4x8 register micro-tile, k-chunks of 16.
// Reads collected == d_out, overwrites same rows after its k-loop (block-local).
// ---------------------------------------------------------------------------
__global__ __launch_bounds__(256) void k_out(
    const float* __restrict__ x, const float* __restrict__ collected,
    const float* __restrict__ Wout, const float* __restrict__ bout,
    float* __restrict__ out)
{
    __shared__ float As[64][20];
    __shared__ float Bs[16][128];
    const int tid = threadIdx.x;
    const int tx  = tid & 15;
    const int ty  = tid >> 4;
    const int row0 = blockIdx.x * 64;

    float acc[4][8];
    #pragma unroll
    for (int i = 0; i < 4; ++i)
        #pragma unroll
        for (int j = 0; j < 8; ++j) acc[i][j] = 0.f;

    for (int k0 = 0; k0 < 192; k0 += 16) {
        {
            const int e = tid * 4;
            const int r = e >> 4, kk = e & 15;
            const float* src = (k0 < 64)
                ? (x + (size_t)(row0 + r) * FIN + (k0 + kk))
                : (collected + (size_t)(row0 + r) * 128 + (k0 - 64 + kk));
            *(float4*)&As[r][kk] = *(const float4*)src;
        }
        #pragma unroll
        for (int rep = 0; rep < 2; ++rep) {
            const int e = (tid + rep * 256) * 4;
            const int kk = e >> 7, c = e & 127;
            *(float4*)&Bs[kk][c] = *(const float4*)(Wout + (size_t)(k0 + kk) * 128 + c);
        }
        __syncthreads();
        #pragma unroll
        for (int kk = 0; kk < 16; ++kk) {
            float a[4];
            #pragma unroll
            for (int i = 0; i < 4; ++i) a[i] = As[ty * 4 + i][kk];
            float4 b0 = *(const float4*)&Bs[kk][tx * 4];
            float4 b1 = *(const float4*)&Bs[kk][64 + tx * 4];
            #pragma unroll
            for (int i = 0; i < 4; ++i) {
                acc[i][0] += a[i] * b0.x; acc[i][1] += a[i] * b0.y;
                acc[i][2] += a[i] * b0.z; acc[i][3] += a[i] * b0.w;
                acc[i][4] += a[i] * b1.x; acc[i][5] += a[i] * b1.y;
                acc[i][6] += a[i] * b1.z; acc[i][7] += a[i] * b1.w;
            }
        }
        __syncthreads();
    }

    #pragma unroll
    for (int i = 0; i < 4; ++i) {
        const int row = row0 + ty * 4 + i;
        float4 o0, o1;
        o0.x = fast_tanh(acc[i][0] + bout[tx*4+0]);
        o0.y = fast_tanh(acc[i][1] + bout[tx*4+1]);
        o0.z = fast_tanh(acc[i][2] + bout[tx*4+2]);
        o0.w = fast_tanh(acc[i][3] + bout[tx*4+3]);
        o1.x = fast_tanh(acc[i][4] + bout[64+tx*4+0]);
        o1.y = fast_tanh(acc[i][5] + bout[64+tx*4+1]);
        o1.z = fast_tanh(acc[i][6] + bout[64+tx*4+2]);
        o1.w = fast_tanh(acc[i][7] + bout[64+tx*4+3]);
        *(float4*)(out + (size_t)row * 128 + tx * 4)      = o0;
        *(float4*)(out + (size_t)row * 128 + 64 + tx * 4) = o1;
    }
}

// ---------------------------------------------------------------------------
extern "C" void kernel_launch(void* const* d_in, const int* in_sizes, int n_in,
                              void* d_out, int out_size, void* d_ws, size_t ws_size,
                              hipStream_t stream)
{
    const float* x    = (const float*)d_in[0];
    // d_in[1] = row_splits: uniform arange(B+1)*V — fixed structure, unused.
    const float* Ws   = (const float*)d_in[2];
    const float* bs   = (const float*)d_in[3];
    const float* Wf   = (const float*)d_in[4];
    const float* bf   = (const float*)d_in[5];
    const float* Wout = (const float*)d_in[6];
    const float* bout = (const float*)d_in[7];
    float* out = (float*)d_out;

    float* coords = (float*)d_ws;                                            // 1 MB
    float* feats  = (float*)((char*)d_ws + (size_t)NN * DD * sizeof(float)); // 16 MB
    float* collected = out;   // reuse d_out as scratch for pooled features

    hipLaunchKernelGGL(k_embed, dim3(NN / 64), dim3(256), 0, stream,
                       x, Ws, bs, Wf, bf, coords, feats);
    hipLaunchKernelGGL(k_knn, dim3(BB * (VV / 16)), dim3(256), 0, stream,
                       coords, feats, collected);
    hipLaunchKernelGGL(k_out, dim3(NN / 64), dim3(256), 0, stream,
                       x, collected, Wout, bout, out);
}